// Round 3
// baseline (121.439 us; speedup 1.0000x reference)
//
#include <hip/hip_runtime.h>
#include <hip/hip_bf16.h>

// RBF network fused kernel for MI355X (gfx950).
// B=131072, D=64, H=512, O=16.
// Grid: 1024 blocks x 256 threads (4 waves). Each block: 128 rows in 8 subtiles of 16.
// Wave w owns h-slice [w*128, (w+1)*128): centroid/weight fragments held in VGPRs
// across the whole block.

#define NDIM 64
#define NHID 512
#define NOUT 16

typedef __attribute__((ext_vector_type(8))) short bf16x8;  // 8 bf16 in 4 VGPRs
typedef __attribute__((ext_vector_type(4))) float f32x4;

#if __has_builtin(__builtin_amdgcn_exp2f)
#define EXP2F(x) __builtin_amdgcn_exp2f(x)
#else
#define EXP2F(x) exp2f(x)
#endif

// fp32 -> bf16 round-to-nearest-even (finite inputs only here)
static __device__ __forceinline__ short f2bf(float f) {
    unsigned int u = __float_as_uint(f);
    unsigned int r = (u + 0x7FFFu + ((u >> 16) & 1u)) >> 16;
    return (short)r;
}

__global__ __launch_bounds__(256, 2)
void rbf_fused(const float* __restrict__ x, const float* __restrict__ cen,
               const float* __restrict__ sig, const float* __restrict__ wgt,
               const float* __restrict__ bias, float* __restrict__ out)
{
    // LDS: x tile (bf16, padded stride 72), xsq, per-wave hidden tile (padded 136),
    // per-wave output partials stored transposed [o][m] so acc2 stores are b128.
    __shared__ __align__(16) short x_lds[16][72];
    __shared__ float xsq_lds[16];
    __shared__ __align__(16) short hid[4][16][136];
    __shared__ __align__(16) float part[4][16][16];

    const int tid   = threadIdx.x;
    const int w     = tid >> 6;    // wave 0..3
    const int lane  = tid & 63;
    const int g     = lane >> 4;   // 16-lane group 0..3
    const int c     = lane & 15;
    const int hbase = w * 128;

    // ---- per-block preload: centroid B-frags + per-h coefficients ----
    // B-frag (16x16x32 bf16): lane needs B[k][n] = centroid[n][k],
    // n = nt*16 + c, k = ks*32 + g*8 + j  (8 contiguous fp32 -> bf16).
    bf16x8 b1[8][2];
    float A2c[8], AHc[8], NBc[8];
#pragma unroll
    for (int nt = 0; nt < 8; ++nt) {
        const int h = hbase + nt * 16 + c;
        const float* cr = cen + (long)h * NDIM + g * 8;
        float csq = 0.f;
        bf16x8 fr0, fr1;
        {
            f32x4 v0 = *(const f32x4*)(cr);
            f32x4 v1 = *(const f32x4*)(cr + 4);
            csq += v0[0]*v0[0] + v0[1]*v0[1] + v0[2]*v0[2] + v0[3]*v0[3];
            csq += v1[0]*v1[0] + v1[1]*v1[1] + v1[2]*v1[2] + v1[3]*v1[3];
            fr0[0]=f2bf(v0[0]); fr0[1]=f2bf(v0[1]); fr0[2]=f2bf(v0[2]); fr0[3]=f2bf(v0[3]);
            fr0[4]=f2bf(v1[0]); fr0[5]=f2bf(v1[1]); fr0[6]=f2bf(v1[2]); fr0[7]=f2bf(v1[3]);
        }
        {
            f32x4 v0 = *(const f32x4*)(cr + 32);
            f32x4 v1 = *(const f32x4*)(cr + 36);
            csq += v0[0]*v0[0] + v0[1]*v0[1] + v0[2]*v0[2] + v0[3]*v0[3];
            csq += v1[0]*v1[0] + v1[1]*v1[1] + v1[2]*v1[2] + v1[3]*v1[3];
            fr1[0]=f2bf(v0[0]); fr1[1]=f2bf(v0[1]); fr1[2]=f2bf(v0[2]); fr1[3]=f2bf(v0[3]);
            fr1[4]=f2bf(v1[0]); fr1[5]=f2bf(v1[1]); fr1[6]=f2bf(v1[2]); fr1[7]=f2bf(v1[3]);
        }
        b1[nt][0] = fr0; b1[nt][1] = fr1;
        // lanes differing in bits 4,5 hold disjoint k-chunks of the same h row
        csq += __shfl_xor(csq, 16);
        csq += __shfl_xor(csq, 32);
        float s = sig[h];
        float a = 1.4426950408889634f / (2.0f * s * s);   // log2(e)/(2 sigma^2)
        a = fminf(a, 1e30f);                               // guard sigma==0 -> no NaN
        A2c[nt] = 2.0f * a;
        AHc[nt] = a;
        NBc[nt] = -a * csq;
    }

    // ---- weight B-frags: B[k][o] = W[hbase + ks*32 + g*8 + j][c] ----
    bf16x8 w2[4];
#pragma unroll
    for (int ks = 0; ks < 4; ++ks) {
        bf16x8 f;
#pragma unroll
        for (int j = 0; j < 8; ++j) {
            f[j] = f2bf(wgt[(hbase + ks * 32 + g * 8 + j) * NOUT + c]);
        }
        w2[ks] = f;
    }
    const float biasv = bias[c];   // epilogue column o == tid&15 == c

    const long rowblock = (long)blockIdx.x * 128;

    for (int ms = 0; ms < 8; ++ms) {
        __syncthreads();  // (A) prev iter consumers of x_lds/part done
        {
            // stage 16 rows of x: thread (r=tid>>4, cc=tid&15) loads float4
            const int r = tid >> 4, cc = tid & 15;
            const float* xp = x + (rowblock + ms * 16 + r) * NDIM + cc * 4;
            f32x4 v = *(const f32x4*)xp;
            float sq = v[0]*v[0] + v[1]*v[1] + v[2]*v[2] + v[3]*v[3];
            sq += __shfl_xor(sq, 1);
            sq += __shfl_xor(sq, 2);
            sq += __shfl_xor(sq, 4);
            sq += __shfl_xor(sq, 8);
            short4 s4;
            s4.x = f2bf(v[0]); s4.y = f2bf(v[1]); s4.z = f2bf(v[2]); s4.w = f2bf(v[3]);
            *(short4*)&x_lds[r][cc * 4] = s4;
            if (cc == 0) xsq_lds[r] = sq;
        }
        __syncthreads();  // (B)

        // A-frags: lane needs x[m=c][k = ks*32 + g*8 + j] -> one b128 each
        bf16x8 af0 = *(const bf16x8*)&x_lds[c][g * 8];
        bf16x8 af1 = *(const bf16x8*)&x_lds[c][32 + g * 8];
        f32x4 xs4 = *(const f32x4*)&xsq_lds[4 * g];   // rows for C-layout (g*4 + r)

        // GEMM1 + RBF activation; write hidden tile (bf16) to this wave's LDS region
#pragma unroll
        for (int nt = 0; nt < 8; ++nt) {
            f32x4 acc = {0.f, 0.f, 0.f, 0.f};
            acc = __builtin_amdgcn_mfma_f32_16x16x32_bf16(af0, b1[nt][0], acc, 0, 0, 0);
            acc = __builtin_amdgcn_mfma_f32_16x16x32_bf16(af1, b1[nt][1], acc, 0, 0, 0);
#pragma unroll
            for (int r = 0; r < 4; ++r) {
                // arg = (2*S - xsq - csq) * log2e/(2 sigma^2)
                float nbx = fmaf(-AHc[nt], xs4[r], NBc[nt]);
                float arg = fmaf(A2c[nt], acc[r], nbx);
                hid[w][4 * g + r][nt * 16 + c] = f2bf(EXP2F(arg));
            }
        }

        // GEMM2 over this wave's K-slice of 128: out_part[16x16]
        f32x4 acc2 = {0.f, 0.f, 0.f, 0.f};
#pragma unroll
        for (int ks = 0; ks < 4; ++ks) {
            bf16x8 a2 = *(const bf16x8*)&hid[w][c][ks * 32 + g * 8];
            acc2 = __builtin_amdgcn_mfma_f32_16x16x32_bf16(a2, w2[ks], acc2, 0, 0, 0);
        }
        // C layout: row m = 4g+r, col o = c. Store transposed [o][m] -> b128.
        *(f32x4*)&part[w][c][4 * g] = acc2;
        __syncthreads();  // (C)

        {
            // epilogue: thread (m=tid>>4, o=tid&15): sum wave partials + bias, normalize
            const int m = tid >> 4, o = tid & 15;
            float v = biasv + part[0][o][m] + part[1][o][m] + part[2][o][m] + part[3][o][m];
            float s = v;
            s += __shfl_xor(s, 1);
            s += __shfl_xor(s, 2);
            s += __shfl_xor(s, 4);
            s += __shfl_xor(s, 8);
            out[(rowblock + ms * 16 + m) * NOUT + o] = v / s;
        }
    }
}

extern "C" void kernel_launch(void* const* d_in, const int* in_sizes, int n_in,
                              void* d_out, int out_size, void* d_ws, size_t ws_size,
                              hipStream_t stream) {
    const float* x    = (const float*)d_in[0];
    const float* cen  = (const float*)d_in[1];
    const float* sig  = (const float*)d_in[2];
    const float* wgt  = (const float*)d_in[3];
    const float* bias = (const float*)d_in[4];
    float* out = (float*)d_out;
    (void)in_sizes; (void)n_in; (void)d_ws; (void)ws_size; (void)out_size;

    rbf_fused<<<dim3(1024), dim3(256), 0, stream>>>(x, cen, sig, wgt, bias, out);
}